// Round 9
// baseline (372.066 us; speedup 1.0000x reference)
//
#include <hip/hip_runtime.h>

#define B_   16
#define SEQ  512
#define MM   514      // SEQ + 2 memory tokens
#define HID  1024
#define NH   16
#define DH   64
#define KP   544      // MM padded to multiple of 32 (zero-padded K for MFMA outg)
#define MTOT (B_ * MM)   // 8224 total A rows across batch
#define UNI  (1.0f/514.0f)

typedef unsigned short us;
typedef __attribute__((ext_vector_type(4))) float f32x4;
typedef __attribute__((ext_vector_type(8))) short short8;     // MFMA bf16 A/B frag
typedef __attribute__((ext_vector_type(8))) _Float16 half8;   // MFMA f16 A/B frag

__device__ __forceinline__ us f2bf(float f) {  // RNE f32->bf16
  unsigned int u = __float_as_uint(f);
  u = (u + 0x7FFFu + ((u >> 16) & 1u)) >> 16;
  return (us)u;
}
__device__ __forceinline__ float bf2f(us h) {
  return __uint_as_float(((unsigned int)h) << 16);
}
__device__ __forceinline__ us f2h(float f) {   // RNE f32->f16 (v_cvt_f16_f32)
  _Float16 h = (_Float16)f;
  return *(us*)&h;
}
// HW packed f32->bf16 (RNE), 2 elems / inst. No builtin on gfx950 — asm (m240).
__device__ __forceinline__ unsigned cvt_pk_bf16(float lo, float hi) {
  unsigned d;
  asm("v_cvt_pk_bf16_f32 %0, %1, %2" : "=v"(d) : "v"(lo), "v"(hi));
  return d;
}

// ---------------------------------------------------------------------------
// K0: prepack — convert A (mem||x / mem||y) and W to bf16 once (in d_out
// scratch; dead until outg overwrites all). (unchanged, verified r6)
// ---------------------------------------------------------------------------
__global__ __launch_bounds__(256) void prepack(
    const float* __restrict__ x, const float* __restrict__ y,
    const float* __restrict__ xm, const float* __restrict__ ym,
    const float* __restrict__ Wx, const float* __restrict__ Wy,
    us* __restrict__ Abf, us* __restrict__ Wbf) {
  const int tid = threadIdx.x;
  const int row = blockIdx.x * 4 + (tid >> 6);
  const int path = blockIdx.y;
  const int lane = tid & 63;
  const float* src;
  us* dst;
  if (row < MTOT) {
    const int gb = row / MM, gt = row - gb * MM;
    const float* tin = path ? y : x;
    const float* mv  = path ? ym : xm;
    src = (gt < 2) ? (mv + (size_t)gt * HID)
                   : (tin + ((size_t)(gb * SEQ + gt - 2)) * HID);
    dst = Abf + ((size_t)(path * MTOT + row)) * HID;
  } else {
    const int o = row - MTOT;
    src = (path ? Wy : Wx) + (size_t)o * HID;
    dst = Wbf + ((size_t)(path * HID + o)) * HID;
  }
  const float* s = src + lane * 16;
  f32x4 v0 = *(const f32x4*)(s);
  f32x4 v1 = *(const f32x4*)(s + 4);
  f32x4 v2 = *(const f32x4*)(s + 8);
  f32x4 v3 = *(const f32x4*)(s + 12);
  uint4 w0, w1;
  w0.x = cvt_pk_bf16(v0[0], v0[1]);  w0.y = cvt_pk_bf16(v0[2], v0[3]);
  w0.z = cvt_pk_bf16(v1[0], v1[1]);  w0.w = cvt_pk_bf16(v1[2], v1[3]);
  w1.x = cvt_pk_bf16(v2[0], v2[1]);  w1.y = cvt_pk_bf16(v2[2], v2[3]);
  w1.z = cvt_pk_bf16(v3[0], v3[1]);  w1.w = cvt_pk_bf16(v3[2], v3[3]);
  *(uint4*)(dst + lane * 16)     = w0;
  *(uint4*)(dst + lane * 16 + 8) = w1;
}

// ---------------------------------------------------------------------------
// K1: proj GEMM from prepacked bf16 (unchanged, verified r6)
// ---------------------------------------------------------------------------
__global__ __launch_bounds__(256) void proj_fused2(
    const us* __restrict__ Abf, const us* __restrict__ Wbf,
    us* __restrict__ Px, us* __restrict__ Py) {
  const int lin = blockIdx.x + 8 * (blockIdx.y + 65 * blockIdx.z);
  const int work = (lin & 7) * 130 + (lin >> 3);
  const int path = (work >= 520) ? 1 : 0;
  const int wrem = work - path * 520;
  const int mt = wrem >> 3, nt = wrem & 7;
  us* P = path ? Py : Px;
  const us* Ab = Abf + (size_t)path * MTOT * HID;
  const us* Wb = Wbf + (size_t)path * HID * HID;

  __shared__ __align__(16) us As[128 * 40];
  __shared__ __align__(16) us Bs[128 * 40];
  const int tid = threadIdx.x;
  const int lane = tid & 63, wave = tid >> 6;
  const int c = lane & 15, q = lane >> 4;
  const int wr = wave >> 1, wc = wave & 1;

  const int srow = tid >> 1, sch = (tid & 1) * 16;
  const int grow = mt * 128 + srow;
  const us* asrc = (grow < MTOT) ? (Ab + (size_t)grow * HID + sch) : nullptr;
  const us* bsrc = Wb + (size_t)(nt * 128 + srow) * HID + sch;
  us* wAp = &As[srow * 40 + sch];
  us* wBp = &Bs[srow * 40 + sch];
  const us* rA = &As[(wr * 64 + c) * 40 + q * 8];
  const us* rB = &Bs[(wc * 64 + c) * 40 + q * 8];

  f32x4 acc[4][4];
#pragma unroll
  for (int i = 0; i < 4; i++)
#pragma unroll
    for (int j = 0; j < 4; j++) acc[i][j] = (f32x4){0.f, 0.f, 0.f, 0.f};

  uint4 z4 = {0u, 0u, 0u, 0u};
  uint4 pa0 = z4, pa1 = z4, pb0, pb1;
  if (asrc) { pa0 = *(const uint4*)asrc; pa1 = *(const uint4*)(asrc + 8); }
  pb0 = *(const uint4*)bsrc; pb1 = *(const uint4*)(bsrc + 8);

  for (int kk = 0; kk < HID; kk += 32) {
    __syncthreads();
    *(uint4*)wAp       = pa0;
    *(uint4*)(wAp + 8) = pa1;
    *(uint4*)wBp       = pb0;
    *(uint4*)(wBp + 8) = pb1;
    __syncthreads();
    if (kk + 32 < HID) {
      if (asrc) {
        pa0 = *(const uint4*)(asrc + kk + 32);
        pa1 = *(const uint4*)(asrc + kk + 32 + 8);
      }
      pb0 = *(const uint4*)(bsrc + kk + 32);
      pb1 = *(const uint4*)(bsrc + kk + 32 + 8);
    }
    short8 a[4], bb[4];
#pragma unroll
    for (int i = 0; i < 4; i++) a[i] = *(const short8*)(rA + i * 16 * 40);
#pragma unroll
    for (int j = 0; j < 4; j++) bb[j] = *(const short8*)(rB + j * 16 * 40);
#pragma unroll
    for (int i = 0; i < 4; i++)
#pragma unroll
      for (int j = 0; j < 4; j++)
        acc[i][j] = __builtin_amdgcn_mfma_f32_16x16x32_bf16(a[i], bb[j], acc[i][j], 0, 0, 0);
  }
#pragma unroll
  for (int i = 0; i < 4; i++) {
#pragma unroll
    for (int r = 0; r < 4; r++) {
      int gr = mt * 128 + wr * 64 + i * 16 + q * 4 + r;
      if (gr < MTOT) {
        size_t rb = (size_t)gr * HID;
#pragma unroll
        for (int j = 0; j < 4; j++)
          P[rb + nt * 128 + wc * 64 + j * 16 + c] = f2bf(acc[i][j][r]);
      }
    }
  }
}

// ---------------------------------------------------------------------------
// shared staging: 64x64 bf16 slab of P (rows clamped), stride 72
// ---------------------------------------------------------------------------
__device__ __forceinline__ void stage_bf(
    us* Xs, const us* P, int b, int r0, int h, int tid) {
#pragma unroll
  for (int i = 0; i < 2; i++) {
    int idx = tid + i * 256;
    int row = idx >> 3, qq = idx & 7;
    *(uint4*)&Xs[row * 72 + qq * 8] =
        *(const uint4*)(P + ((size_t)(b * MM + min(r0 + row, MM - 1))) * HID + h * DH + qq * 8);
  }
}

// ---------------------------------------------------------------------------
// K2 (r9): sums_v3. One block per (b, h, 128-col n-chunk); 512 thr (8 waves
// = 4 m-strips x 2 col-groups of 64). LDS ~31 KB -> 4 blocks/CU (vs 2 at
// 60 KB) — occupancy was the r8 limiter. Math body identical to verified
// r6/r8 version; only geometry changed. XCD-chunked remap (1280 = 8*160).
// ---------------------------------------------------------------------------
__global__ __launch_bounds__(512) void sums_v3(
    const us* __restrict__ Px, const us* __restrict__ Py,
    const int* __restrict__ mx, const int* __restrict__ my,
    float* __restrict__ Sums) {
  const int lin = blockIdx.x;
  const int work = (lin & 7) * 160 + (lin >> 3);
  const int b = work / 80;
  const int rem = work - b * 80;
  const int h = rem / 5;
  const int nc = rem - h * 5;       // 128-col chunk index, 0..4
  const int n0 = nc * 128;
  __shared__ __align__(16) us Ys[128 * 72];   // 18.4 KB
  __shared__ __align__(16) us Xs[64 * 72];    //  9.2 KB
  __shared__ float cS[128];
  __shared__ int myS[128];
  __shared__ int mxS[576];
  const int tid = threadIdx.x;
  const int lane = tid & 63, wave = tid >> 6;
  const int c = lane & 15, q = lane >> 4;
  const int strip = wave & 3, cgrp = wave >> 2;   // cgrp picks 64-col half

  for (int i = tid; i < 128; i += 512) {
    cS[i] = 0.f;
    int n = n0 + i;
    myS[i] = (n >= MM) ? 0 : ((n < 2) ? 1 : my[b * SEQ + n - 2]);
  }
  for (int i = tid; i < 576; i += 512)
    mxS[i] = (i >= MM) ? 0 : ((i < 2) ? 1 : mx[b * SEQ + i - 2]);
  {
    // stage Y chunk: 128 rows x 8 qq-chunks = 1024 units, 2/thread
#pragma unroll
    for (int it = 0; it < 2; it++) {
      int idx = tid + it * 512;
      int row = idx >> 3, qq = idx & 7;
      int grow = min(n0 + row, MM - 1);
      *(uint4*)&Ys[row * 72 + qq * 8] =
          *(const uint4*)(Py + ((size_t)(b * MM + grow)) * HID + h * DH + qq * 8);
    }
  }
  __syncthreads();

  const size_t base = ((size_t)(b * NH + h)) * MM;
  const size_t COLOFF = (size_t)B_ * NH * MM;

  for (int mt = 0; mt < 9; mt++) {
    {
      const int row8 = tid >> 3, qq = tid & 7;
      int grow = min(mt * 64 + row8, MM - 1);
      *(uint4*)&Xs[row8 * 72 + qq * 8] =
          *(const uint4*)(Px + ((size_t)(b * MM + grow)) * HID + h * DH + qq * 8);
    }
    __syncthreads();
    short8 a0 = *(const short8*)&Xs[(strip * 16 + c) * 72 + q * 8];
    short8 a1 = *(const short8*)&Xs[(strip * 16 + c) * 72 + q * 8 + 32];
    int rm[4];
#pragma unroll
    for (int r = 0; r < 4; r++) rm[r] = mxS[mt * 64 + strip * 16 + q * 4 + r];
    float rowp[4] = {0.f, 0.f, 0.f, 0.f};
#pragma unroll
    for (int ss = 0; ss < 4; ss++) {
      int nloc = cgrp * 64 + ss * 16 + c;
      short8 b0 = *(const short8*)&Ys[nloc * 72 + q * 8];
      short8 b1 = *(const short8*)&Ys[nloc * 72 + q * 8 + 32];
      f32x4 av = (f32x4){0.f, 0.f, 0.f, 0.f};
      av = __builtin_amdgcn_mfma_f32_16x16x32_bf16(a0, b0, av, 0, 0, 0);
      av = __builtin_amdgcn_mfma_f32_16x16x32_bf16(a1, b1, av, 0, 0, 0);
      int cmv = myS[nloc];
      float colp = 0.f;
#pragma unroll
      for (int r = 0; r < 4; r++) {
        float e = (rm[r] && cmv) ? __expf(av[r]) : 0.f;
        rowp[r] += e;
        colp += e;
      }
      colp += __shfl_xor(colp, 16);
      colp += __shfl_xor(colp, 32);
      if (q == 0) atomicAdd(&cS[nloc], colp);   // LDS atomic, block-local
    }
#pragma unroll
    for (int d = 1; d < 16; d <<= 1)
#pragma unroll
      for (int r = 0; r < 4; r++) rowp[r] += __shfl_xor(rowp[r], d, 16);
    if (c == 0) {
#pragma unroll
      for (int r = 0; r < 4; r++) {
        int m = mt * 64 + strip * 16 + q * 4 + r;
        if (m < MM) atomicAdd(&Sums[base + m], rowp[r]);
      }
    }
    __syncthreads();   // Xs reuse + cS visibility for next iter
  }
  for (int i = tid; i < 128; i += 512) {
    int n = n0 + i;
    if (n < MM) atomicAdd(&Sums[COLOFF + base + n], cS[i]);
  }
}

// ---------------------------------------------------------------------------
// K2b: invert sums in place (unchanged)
// ---------------------------------------------------------------------------
__global__ __launch_bounds__(256) void inv_kernel(float* __restrict__ Sums) {
  int i = blockIdx.x * 256 + threadIdx.x;
  if (i < 2 * B_ * NH * MM) {
    float s = Sums[i];
    Sums[i] = (s > 0.f) ? (1.f / s) : -1.f;
  }
}

// ---------------------------------------------------------------------------
// K3: attn — r6-verified 64x64/256-thread body + XCD-chunked remap
// (unchanged from r8 — verified 365us run)
// ---------------------------------------------------------------------------
__global__ __launch_bounds__(256) void attn_swz(
    const us* __restrict__ Px, const us* __restrict__ Py,
    const int* __restrict__ mx, const int* __restrict__ my,
    const float* __restrict__ Inv,
    us* __restrict__ attnXT, us* __restrict__ attnY) {
  const int lin = blockIdx.x;
  const int work = (lin & 7) * 162 + (lin >> 3);
  const int b = work / 81;
  const int rem = work - b * 81;
  const int mt = rem / 9;
  const int nt = rem - mt * 9;
  __shared__ __align__(16) us Xs[64 * 72];
  __shared__ __align__(16) us Ys[64 * 72];
  const int tid = threadIdx.x;
  const int lane = tid & 63, wave = tid >> 6;
  const int c = lane & 15, q = lane >> 4;
  const size_t COLOFF = (size_t)B_ * NH * MM;

  int mreg[4], rm[4], ncol[4], cm[4];
#pragma unroll
  for (int r = 0; r < 4; r++) {
    mreg[r] = mt * 64 + wave * 16 + q * 4 + r;
    rm[r] = (mreg[r] >= MM) ? 0 : ((mreg[r] < 2) ? 1 : mx[b * SEQ + mreg[r] - 2]);
  }
#pragma unroll
  for (int s = 0; s < 4; s++) {
    ncol[s] = nt * 64 + s * 16 + c;
    cm[s] = (ncol[s] >= MM) ? 0 : ((ncol[s] < 2) ? 1 : my[b * SEQ + ncol[s] - 2]);
  }

  float aX[4][4], aY[4][4];
#pragma unroll
  for (int s = 0; s < 4; s++)
#pragma unroll
    for (int r = 0; r < 4; r++) { aX[s][r] = 0.f; aY[s][r] = 0.f; }

  for (int h = 0; h < NH; h++) {
    __syncthreads();
    stage_bf(Xs, Px, b, mt * 64, h, tid);
    stage_bf(Ys, Py, b, nt * 64, h, tid);
    __syncthreads();
    short8 a0 = *(const short8*)&Xs[(wave * 16 + c) * 72 + q * 8];
    short8 a1 = *(const short8*)&Xs[(wave * 16 + c) * 72 + q * 8 + 32];
    const size_t base = ((size_t)(b * NH + h)) * MM;
    float invR[4];
#pragma unroll
    for (int r = 0; r < 4; r++) invR[r] = Inv[base + min(mreg[r], MM - 1)];
#pragma unroll
    for (int s = 0; s < 4; s++) {
      float invC = Inv[COLOFF + base + min(ncol[s], MM - 1)];
      short8 b0 = *(const short8*)&Ys[(s * 16 + c) * 72 + q * 8];
      short8 b1 = *(const short8*)&Ys[(s * 16 + c) * 72 + q * 8 + 32];
      f32x4 av = (f32x4){0.f, 0.f, 0.f, 0.f};
      av = __builtin_amdgcn_mfma_f32_16x16x32_bf16(a0, b0, av, 0, 0, 0);
      av = __builtin_amdgcn_mfma_f32_16x16x32_bf16(a1, b1, av, 0, 0, 0);
#pragma unroll
      for (int r = 0; r < 4; r++) {
        float e = (rm[r] && cm[s]) ? __expf(av[r]) : 0.f;
        aY[s][r] += (invR[r] < 0.f) ? UNI : e * invR[r];
        aX[s][r] += (invC < 0.f) ? UNI : e * invC;
      }
    }
  }
#pragma unroll
  for (int s = 0; s < 4; s++) {
    if (ncol[s] < MM) {
      us* xrow = attnXT + ((size_t)(b * MM + ncol[s])) * KP;
      if (mreg[3] < MM) {   // fast packed 4xf16 store (mreg[0] % 4 == 0)
        uint2 w;
        w.x = (unsigned)f2h(aX[s][0] * 0.0625f) | ((unsigned)f2h(aX[s][1] * 0.0625f) << 16);
        w.y = (unsigned)f2h(aX[s][2] * 0.0625f) | ((unsigned)f2h(aX[s][3] * 0.0625f) << 16);
        *(uint2*)&xrow[mreg[0]] = w;
      } else {
#pragma unroll
        for (int r = 0; r < 4; r++)
          if (mreg[r] < MM) xrow[mreg[r]] = f2h(aX[s][r] * 0.0625f);
      }
#pragma unroll
      for (int r = 0; r < 4; r++)
        if (mreg[r] < MM)
          attnY[((size_t)(b * MM + mreg[r])) * KP + ncol[s]] = f2h(aY[s][r] * 0.0625f);
    }
  }
}

// ---------------------------------------------------------------------------
// K3b (fused): XT[b][o][k] = f16(Mem(k,o)) for both paths (unchanged)
// ---------------------------------------------------------------------------
__global__ __launch_bounds__(256) void transpose_fused(
    const float* __restrict__ x, const float* __restrict__ y,
    const float* __restrict__ xm, const float* __restrict__ ym,
    us* __restrict__ XTx, us* __restrict__ XTy) {
  const int kt = blockIdx.x, ot = blockIdx.y;
  const int b = blockIdx.z & 15, path = blockIdx.z >> 4;
  const float* tin  = path ? y  : x;
  const float* mvec = path ? ym : xm;
  us* XT            = path ? XTy : XTx;
  __shared__ __align__(16) us T[64 * 40];
  const int tid = threadIdx.x;
  {
    const int row = tid >> 3;          // k-local 0..31
    const int col8 = (tid & 7) * 8;    // o-local chunk
    const int kg = kt * 32 + row;
    const float* src = (kg < 2) ? (mvec + (size_t)kg * HID + ot * 64 + col8)
                     : (kg < MM) ? (tin + ((size_t)(b * SEQ + kg - 2)) * HID + ot * 64 + col8)
                                 : nullptr;
    f32x4 v0 = (f32x4){0.f, 0.f, 0.f, 0.f};
    f32x4 v1 = (f32x4){0.f, 0.f, 0.f, 0.f};
    if (src) { v0 = *(const f32x4*)src; v1 = *(const f32x4*)(src + 4); }
#pragma unroll
    for (int j = 0; j < 4; j++) T[(col8 + j) * 40 + row] = f2h(v0[j]);
#pragma unroll
    for (int j = 0; j < 4; j++) T[(col8 + 4 + j) * 40 + row] = f2h(v1[j]);
  }
  __syncthreads();
  const int orow = tid >> 2, kc = (tid & 3) * 8;
  uint4 w = *(const uint4*)&T[orow * 40 + kc];
  *(uint4*)&XT[((size_t)(b * HID + ot * 64 + orow)) * KP + kt * 32 + kc] = w;
}

// ---------------------------------------------------------------------------
// K4 (fused): MFMA output GEMM for both paths (unchanged)
// ---------------------------------------------------------------------------
__global__ __launch_bounds__(256) void outg_fused(
    const us* __restrict__ A0, const us* __restrict__ A1,
    const us* __restrict__ XTx, const us* __restrict__ XTy,
    float* __restrict__ outp) {
  const int ot = blockIdx.x, rt = blockIdx.y;
  const int b = blockIdx.z & 15, path = blockIdx.z >> 4;
  const us* A  = path ? A1 : A0;
  const us* XT = path ? XTy : XTx;
  float* op = outp + (path ? (size_t)B_ * SEQ * HID : 0);
  const int r0 = rt * 128, o0 = ot * 128;
  __shared__ __align__(16) us As[128 * 40];
  __shared__ __align__(16) us Bs[128 * 40];
  const int tid = threadIdx.x;
  const int lane = tid & 63, wave = tid >> 6;
  const int c = lane & 15, q = lane >> 4;
  const int wr = wave >> 1, wc = wave & 1;

  const int srow = tid >> 2, sch = (tid & 3) * 8;
  const us* gA0 = A + ((size_t)(b * MM + 2 + r0 + srow)) * KP + sch;
  const us* gA1 = gA0 + (size_t)64 * KP;
  const us* gB0 = XT + ((size_t)(b * HID + o0 + srow)) * KP + sch;
  const us* gB1 = gB0 + (size_t)64 * KP;
  us* wA0 = &As[srow * 40 + sch];
  us* wA1 = wA0 + 64 * 40;
  us* wB0 = &Bs[srow * 40 + sch];
  us* wB1 = wB0 + 64 * 40;

  f32x4 acc[4][4];
#pragma unroll
  for (int i = 0; i < 4; i++)
#pragma unroll
    for (int j = 0; j < 4; j++) acc[i][j] = (f32x4){0.f, 0.f, 0.f, 0.f};

  const us* rA = &As[(wr * 64 + c) * 40 + q * 8];
  const us* rB = &Bs[(wc * 64 + c) * 40 + q * 8];

  uint4 pA0 = *(const uint4*)gA0;
  uint4 pA1 = *(const uint4*)gA1;
  uint4 pB0 = *(const uint4*)gB0;
  uint4 pB1 = *(const uint4*)gB1;

  for (int kk = 0; kk < KP; kk += 32) {
    __syncthreads();
    *(uint4*)wA0 = pA0;
    *(uint4*)wA1 = pA1;
    *(uint4*)wB0 = pB0;
    *(uint4*)wB1 = pB1;
    __syncthreads();
    if (kk + 32 < KP) {
      pA0 = *(const uint4*)(gA0 + kk + 32);
      pA1 = *(const uint4*)(gA1 + kk + 32);
      pB0 = *(const uint4*)(gB0 + kk + 32);
      pB1 = *(const uint4*)(gB1 + kk + 32);
    }
    half8 a[4], bb[4];
#pragma unroll
    for (int i = 0; i < 4; i++) a[i] = *(const half8*)(rA + i * 16 * 40);
#pragma unroll
    for (int j = 0; j < 4; j++) bb[j] = *(const half8*)(rB + j * 16 * 40);
#pragma unroll
    for (int i = 0; i < 4; i++)
#pragma unroll
      for (int j = 0; j < 4; j++)
        acc[i][j] = __builtin_amdgcn_mfma_f32_16x16x32_f16(a[i], bb[j], acc[i][j], 0, 0, 0);
  }
#pragma unroll
  for (int i = 0; i < 4; i++) {
#pragma unroll
    for (int rr = 0; rr < 4; rr++) {
      int r = r0 + wr * 64 + i * 16 + q * 4 + rr;
      size_t rowbase = ((size_t)(b * SEQ + r)) * HID;
#pragma unroll
      for (int j = 0; j < 4; j++)
        op[rowbase + o0 + wc * 64 + j * 16 + c] = acc[i][j][rr];
    }
  }
}

// ---------------------------------------------------------------------------
// Fallback path kernels (old bf16 attn + f32 outg)
// ---------------------------------------------------------------------------
__global__ __launch_bounds__(256) void attn_mfma_old(
    const us* __restrict__ Px, const us* __restrict__ Py,
    const int* __restrict__ mx, const int* __restrict__ my,
    const float* __restrict__ Inv,
    us* __restrict__ attnX, us* __restrict__ attnY,
    const int doX, const int doY) {
  const int nt = blockIdx.x, mt = blockIdx.y, b = blockIdx.z;
  __shared__ __align__(16) us Xs[64 * 72];
  __shared__ __align__(16) us Ys[64 * 72];
  const int tid = threadIdx.x;
  const int lane = tid & 63, wave = tid >> 6;
  const int c = lane & 15, q = lane >> 4;
  const size_t COLOFF = (size_t)B_ * NH * MM;

  int mreg[4], rm[4], ncol[4], cm[4];
#pragma unroll
  for (int r = 0; r < 4; r++) {
    mreg[r] = mt * 64 + wave * 16 + q * 4 + r;
    rm[r] = (mreg[r] >= MM) ? 0 : ((mreg[r] < 2) ? 1 : mx[b * SEQ + mreg[r] - 2]);
  }
#pragma unroll
  for (int s = 0; s < 4; s++) {
    ncol[s] = nt * 64 + s * 16 + c;
    cm[s] = (ncol[s] >= MM) ? 0 : ((ncol[s] < 2) ? 1 : my[b * SEQ + ncol[s] - 2]);
  }

  float aX[4][4], aY[4][4];
#pragma unroll
  for (int s = 0; s < 4; s++)
#pragma unroll
    for (int r = 0; r < 4; r++) { aX[s][r] = 0.f; aY[s][r] = 0.f; }

  for (int h = 0; h < NH; h++) {
    __syncthreads();
    stage_bf(Xs, Px, b, mt * 64, h, tid);
    stage_bf(Ys, Py, b, nt * 64, h, tid);
    __syncthreads();
    short8 a0 = *(const short8*)&Xs[(wave * 16 + c) * 72 + q * 8];
    short8 a1 = *(const short8*)&Xs[(wave * 16 + c) * 72 + q * 8 + 32];
    const size_t base = ((size_t)(b * NH + h)) * MM;
    float invR[4];
#pragma unroll
    for (int r = 0; r < 4; r++) invR[r] = Inv[base + min(mreg[r], MM - 1)];
#pragma unroll
    for (int s = 0; s < 4; s++) {
      float invC = Inv[COLOFF + base + min(ncol[s], MM - 1)];
      short8 b0 = *(const short8*)&Ys[(s * 16 + c) * 72 + q * 8];
      short8 b1 = *(const short8*)&Ys[(s * 16 + c) * 72 + q * 8 + 32];
      f32x4 av = (f32x4){0.f, 0.f, 0.f, 0.f};
      av = __builtin_amdgcn_mfma_f32_16x16x32_bf16(a0, b0, av, 0, 0, 0);
      av = __builtin_amdgcn_mfma_f32_16x16x32_bf16(a1, b1, av, 0, 0, 0);
#pragma unroll
      for (int r = 0; r < 4; r++) {
        float e = (rm[r] && cm[s]) ? __expf(av[r]) : 0.f;
        aY[s][r] += (invR[r] < 0.f) ? UNI : e * invR[r];
        aX[s][r] += (invC < 0.f) ? UNI : e * invC;
      }
    }
  }
#pragma unroll
  for (int s = 0; s < 4; s++) {
#pragma unroll
    for (int r = 0; r < 4; r++) {
      if (mreg[r] < MM && ncol[s] < MM) {
        size_t idx = ((size_t)(b * MM + mreg[r])) * MM + ncol[s];
        if (doX) attnX[idx] = f2bf(aX[s][r] * 0.0625f);
        if (doY) attnY[idx] = f2bf(aY[s][r] * 0.0625f);
      }
    }
  }
}

__global__ __launch_bounds__(256) void outg_kernel(
    const us* __restrict__ attn, const float* __restrict__ tin,
    const float* __restrict__ mvec, float* __restrict__ outp, const int trans) {
  const int otile = blockIdx.x, rtile = blockIdx.y, b = blockIdx.z;
  __shared__ __align__(16) float Ss[32 * 132];
  __shared__ __align__(16) float Ms[32 * 132];
  const int tid = threadIdx.x;
  const int r0 = rtile * 128, o0 = otile * 128;

  float acc[8][8];
#pragma unroll
  for (int i = 0; i < 8; i++)
#pragma unroll
    for (int j = 0; j < 8; j++) acc[i][j] = 0.f;

  for (int kk = 0; kk < 544; kk += 32) {
    __syncthreads();
    if (trans) {
      int rq = (tid & 31) * 4;
      int kr = tid >> 5;
#pragma unroll
      for (int kb = 0; kb < 32; kb += 8) {
        int k = kr + kb;
        int kg = kk + k;
        if (kg < MM) {
          const us* src = attn + ((size_t)(b * MM + kg)) * MM + 2 + r0 + rq;
          Ss[k * 132 + rq + 0] = bf2f(src[0]);
          Ss[k * 132 + rq + 1] = bf2f(src[1]);
          Ss[k * 132 + rq + 2] = bf2f(src[2]);
          Ss[k * 132 + rq + 3] = bf2f(src[3]);
        } else {
          Ss[k * 132 + rq + 0] = 0.f;
          Ss[k * 132 + rq + 1] = 0.f;
          Ss[k * 132 + rq + 2] = 0.f;
          Ss[k * 132 + rq + 3] = 0.f;
        }
      }
    } else {
      int r = tid >> 1;
      int kh = (tid & 1) * 16;
      const us* src = attn + ((size_t)(b * MM + 2 + r0 + r)) * MM;
#pragma unroll
      for (int j = 0; j < 16; j++) {
        int k = kh + j;
        int kg = kk + k;
        Ss[k * 132 + r] = (kg < MM) ? bf2f(src[kg]) : 0.f;
      }
    }
    {
      int k = tid >> 3;
      int oq = (tid & 7) * 16;
      int kg = kk + k;
      const float* mr = (kg < 2) ? (mvec + (size_t)kg * HID)
                      : (kg < MM) ? (tin + ((size_t)(b * SEQ + kg - 2)) * HID)
                                  : nullptr;
#pragma unroll
      for (int qq = 0; qq < 4; qq++) {
        f32x4 v = (f32x4){0.f, 0.f, 0.f, 0.f};
        if (mr) v = *(const f32x4*)(mr + o0 + oq + qq * 4);
        *(f32x4*)&Ms[k * 132 + oq + qq * 4] = v;
      }
    }
    __syncthreads();
    const int ty = tid >> 4, tx = tid & 15;
    for (int k = 0; k < 32; k++) {
      f32x4 s0 = *(const f32x4*)&Ss[k * 132 + ty * 4];
      f32x4 s1 = *(const f32x4*)&Ss[k * 132 + 64 + ty * 4];
      f32x4 m0 = *(const f32x4*)&Ms[k * 132 + tx * 4];
      f32x4 m1 = *(const f32x4*)&Ms[k * 132 + 64 + tx * 4];
#pragma unroll
      for (int i = 0; i < 4; i++) {
#pragma unroll
        for (int j = 0; j < 4; j++) {
          acc[i][j]         += s0[i] * m0[j];
          acc[i][j + 4]     += s0[i] * m1[j];
          acc[i + 4][j]     += s1[i] * m0[j];
          acc[i + 4][j + 4] += s1[i] * m1[j];
        }
      }
    }
  }
  const int ty = tid >> 4, tx = tid & 15;
#pragma unroll
  for (int ri = 0; ri < 2; ri++) {
#pragma unroll
    for (int i = 0; i < 4; i++) {
      int r = r0 + ri * 64 + ty * 4 + i;
      size_t rowbase = ((size_t)(b * SEQ + r)) * HID;
#pragma unroll
      for (int oi = 0; oi < 2; oi++) {
        int o = o0 + oi * 64 + tx * 4;
        f32x4 v;
#pragma unroll
        for (int j = 0; j < 4; j++) v[j] = acc[ri * 4 + i][oi * 4 + j];
        *(f32x4*)&outp[rowbase + o] = v;
      }
    }
  }
}

// ---------------------------------------------------------------------------
extern "C" void kernel_launch(void* const* d_in, const int* in_sizes, int n_in,
                              void* d_out, int out_size, void* d_ws, size_t ws_size,
                              hipStream_t stream) {
  const float* x  = (const float*)d_in[0];
  const float* y  = (const float*)d_in[1];
  const int* mask_x = (const int*)d_in[2];
  const int* mask_y = (const int*)d_in[3];
  const float* Wx = (const float*)d_in[4];
  const float* Wy = (const float*)d_in[5];
  const float* xm = (const float*)d_in[6];
  const float* ym = (const float*)d_in[7];
  float* out = (float*)d_out;

  const size_t szSums = (size_t)2 * B_ * NH * MM * 4;   //  1,052,672
  const size_t szP    = (size_t)B_ * MM * HID * 2;      // 16,842,752 (bf16)
  const size_t szAtt  = (size_t)B_ * MM * MM * 2;       //  8,454,272 (bf16, old)
  const size_t szAttP = (size_t)B_ * MM * KP * 2;       //  8,947,712 (f16, padded)
  const size_t szXT   = (size_t)B_ * HID * KP * 2;      // 17,825,792 (f16)
  const size_t R_off  = szSums + 2 * szAttP;            // P / XT region start
  const size_t needNew = R_off + 2 * szXT;              // 54,599,680

  char* ws = (char*)d_ws;

  // prepack scratch lives in d_out (67 MB; dead until outg rewrites all of it)
  us* Abf = (us*)d_out;                                  // 33.7 MB
  us* Wbf = (us*)d_out + (size_t)2 * MTOT * HID;         //  4.2 MB

  if (ws_size >= needNew) {
    // ---- MFMA output path ----
    float* Sums = (float*)ws;
    us* A0  = (us*)(ws + szSums);            // attnX transposed, [MM][KP] f16
    us* A1  = (us*)(ws + szSums + szAttP);   // attnY,           [MM][KP] f16
    us* Px  = (us*)(ws + R_off);
    us* Py  = (us*)(ws + R_off + szP);
    us* XTx = (us*)(ws + R_off);             // overlaps Px/Py — P dead by then
    us* XTy = (us*)(ws + R_off + szXT);

    prepack<<<dim3((MTOT + HID) / 4, 2), 256, 0, stream>>>(x, y, xm, ym, Wx, Wy, Abf, Wbf);
    proj_fused2<<<dim3(8, 65, 2), 256, 0, stream>>>(Abf, Wbf, Px, Py);
    hipMemsetAsync(Sums, 0, szSums, stream);
    hipMemsetAsync(A0, 0, 2 * szAttP, stream);   // zero pad cols for K-tail
    sums_v3<<<dim3(1280), 512, 0, stream>>>(Px, Py, mask_x, mask_y, Sums);
    inv_kernel<<<dim3((2 * B_ * NH * MM + 255) / 256), 256, 0, stream>>>(Sums);
    attn_swz<<<dim3(1296), 256, 0, stream>>>(Px, Py, mask_x, mask_y, Sums, A0, A1);
    transpose_fused<<<dim3(17, 16, 32), 256, 0, stream>>>(x, y, xm, ym, XTx, XTy);
    outg_fused<<<dim3(8, 4, 32), 256, 0, stream>>>(A0, A1, XTx, XTy, out);
    return;
  }

  // ---- fallback: previous verified path ----
  const int dual = (ws_size >= szSums + 2 * szP + 2 * szAtt) ? 1 : 0;
  float* Sums = (float*)(ws);
  us* Px = (us*)(ws + szSums);
  us* Py = (us*)(ws + szSums + szP);
  us* A0 = (us*)(ws + szSums + 2 * szP);
  us* A1 = dual ? (us*)(ws + szSums + 2 * szP + szAtt) : A0;

  prepack<<<dim3((MTOT + HID) / 4, 2), 256, 0, stream>>>(x, y, xm, ym, Wx, Wy, Abf, Wbf);
  proj_fused2<<<dim3(8, 65, 2), 256, 0, stream>>>(Abf, Wbf, Px, Py);
  hipMemsetAsync(Sums, 0, szSums, stream);
  sums_v3<<<dim3(1280), 512, 0, stream>>>(Px, Py, mask_x, mask_y, Sums);
  inv_kernel<<<dim3((2 * B_ * NH * MM + 255) / 256), 256, 0, stream>>>(Sums);

  if (dual) {
    attn_mfma_old<<<dim3(9, 9, 16), 256, 0, stream>>>(Px, Py, mask_x, mask_y, Sums, A0, A1, 1, 1);
    outg_kernel<<<dim3(8, 4, 16), 256, 0, stream>>>(A0, x, xm, out, 1);
    outg_kernel<<<dim3(8, 4, 16), 256, 0, stream>>>(A1, y, ym, out + (size_t)B_ * SEQ * HID, 0);
  } else {
    attn_mfma_old<<<dim3(9, 9, 16), 256, 0, stream>>>(Px, Py, mask_x, mask_y, Sums, A0, A0, 1, 0);
    outg_kernel<<<dim3(8, 4, 16), 256, 0, stream>>>(A0, x, xm, out, 1);
    attn_mfma_old<<<dim3(9, 9, 16), 256, 0, stream>>>(Px, Py, mask_x, mask_y, Sums, A0, A0, 0, 1);
    outg_kernel<<<dim3(8, 4, 16), 256, 0, stream>>>(A0, y, ym, out + (size_t)B_ * SEQ * HID, 0);
  }
}

// Round 10
// 349.444 us; speedup vs baseline: 1.0647x; 1.0647x over previous
//
#include <hip/hip_runtime.h>

#define B_   16
#define SEQ  512
#define MM   514      // SEQ + 2 memory tokens
#define HID  1024
#define NH   16
#define DH   64
#define KP   544      // MM padded to multiple of 32 (zero-padded K for MFMA outg)
#define MTOT (B_ * MM)   // 8224 total A rows across batch
#define UNI  (1.0f/514.0f)

typedef unsigned short us;
typedef __attribute__((ext_vector_type(4))) float f32x4;
typedef __attribute__((ext_vector_type(8))) short short8;     // MFMA bf16 A/B frag
typedef __attribute__((ext_vector_type(8))) _Float16 half8;   // MFMA f16 A/B frag

__device__ __forceinline__ us f2bf(float f) {  // RNE f32->bf16
  unsigned int u = __float_as_uint(f);
  u = (u + 0x7FFFu + ((u >> 16) & 1u)) >> 16;
  return (us)u;
}
__device__ __forceinline__ float bf2f(us h) {
  return __uint_as_float(((unsigned int)h) << 16);
}
__device__ __forceinline__ us f2h(float f) {   // RNE f32->f16 (v_cvt_f16_f32)
  _Float16 h = (_Float16)f;
  return *(us*)&h;
}
// HW packed f32->bf16 (RNE), 2 elems / inst. No builtin on gfx950 — asm (m240).
__device__ __forceinline__ unsigned cvt_pk_bf16(float lo, float hi) {
  unsigned d;
  asm("v_cvt_pk_bf16_f32 %0, %1, %2" : "=v"(d) : "v"(lo), "v"(hi));
  return d;
}

// ---------------------------------------------------------------------------
// K0: prepack — convert A (mem||x / mem||y) and W to bf16 once (in d_out
// scratch; dead until outg overwrites all). (unchanged, verified r6)
// ---------------------------------------------------------------------------
__global__ __launch_bounds__(256) void prepack(
    const float* __restrict__ x, const float* __restrict__ y,
    const float* __restrict__ xm, const float* __restrict__ ym,
    const float* __restrict__ Wx, const float* __restrict__ Wy,
    us* __restrict__ Abf, us* __restrict__ Wbf) {
  const int tid = threadIdx.x;
  const int row = blockIdx.x * 4 + (tid >> 6);
  const int path = blockIdx.y;
  const int lane = tid & 63;
  const float* src;
  us* dst;
  if (row < MTOT) {
    const int gb = row / MM, gt = row - gb * MM;
    const float* tin = path ? y : x;
    const float* mv  = path ? ym : xm;
    src = (gt < 2) ? (mv + (size_t)gt * HID)
                   : (tin + ((size_t)(gb * SEQ + gt - 2)) * HID);
    dst = Abf + ((size_t)(path * MTOT + row)) * HID;
  } else {
    const int o = row - MTOT;
    src = (path ? Wy : Wx) + (size_t)o * HID;
    dst = Wbf + ((size_t)(path * HID + o)) * HID;
  }
  const float* s = src + lane * 16;
  f32x4 v0 = *(const f32x4*)(s);
  f32x4 v1 = *(const f32x4*)(s + 4);
  f32x4 v2 = *(const f32x4*)(s + 8);
  f32x4 v3 = *(const f32x4*)(s + 12);
  uint4 w0, w1;
  w0.x = cvt_pk_bf16(v0[0], v0[1]);  w0.y = cvt_pk_bf16(v0[2], v0[3]);
  w0.z = cvt_pk_bf16(v1[0], v1[1]);  w0.w = cvt_pk_bf16(v1[2], v1[3]);
  w1.x = cvt_pk_bf16(v2[0], v2[1]);  w1.y = cvt_pk_bf16(v2[2], v2[3]);
  w1.z = cvt_pk_bf16(v3[0], v3[1]);  w1.w = cvt_pk_bf16(v3[2], v3[3]);
  *(uint4*)(dst + lane * 16)     = w0;
  *(uint4*)(dst + lane * 16 + 8) = w1;
}

// ---------------------------------------------------------------------------
// K1: proj GEMM from prepacked bf16 (unchanged, verified r6)
// ---------------------------------------------------------------------------
__global__ __launch_bounds__(256) void proj_fused2(
    const us* __restrict__ Abf, const us* __restrict__ Wbf,
    us* __restrict__ Px, us* __restrict__ Py) {
  const int lin = blockIdx.x + 8 * (blockIdx.y + 65 * blockIdx.z);
  const int work = (lin & 7) * 130 + (lin >> 3);
  const int path = (work >= 520) ? 1 : 0;
  const int wrem = work - path * 520;
  const int mt = wrem >> 3, nt = wrem & 7;
  us* P = path ? Py : Px;
  const us* Ab = Abf + (size_t)path * MTOT * HID;
  const us* Wb = Wbf + (size_t)path * HID * HID;

  __shared__ __align__(16) us As[128 * 40];
  __shared__ __align__(16) us Bs[128 * 40];
  const int tid = threadIdx.x;
  const int lane = tid & 63, wave = tid >> 6;
  const int c = lane & 15, q = lane >> 4;
  const int wr = wave >> 1, wc = wave & 1;

  const int srow = tid >> 1, sch = (tid & 1) * 16;
  const int grow = mt * 128 + srow;
  const us* asrc = (grow < MTOT) ? (Ab + (size_t)grow * HID + sch) : nullptr;
  const us* bsrc = Wb + (size_t)(nt * 128 + srow) * HID + sch;
  us* wAp = &As[srow * 40 + sch];
  us* wBp = &Bs[srow * 40 + sch];
  const us* rA = &As[(wr * 64 + c) * 40 + q * 8];
  const us* rB = &Bs[(wc * 64 + c) * 40 + q * 8];

  f32x4 acc[4][4];
#pragma unroll
  for (int i = 0; i < 4; i++)
#pragma unroll
    for (int j = 0; j < 4; j++) acc[i][j] = (f32x4){0.f, 0.f, 0.f, 0.f};

  uint4 z4 = {0u, 0u, 0u, 0u};
  uint4 pa0 = z4, pa1 = z4, pb0, pb1;
  if (asrc) { pa0 = *(const uint4*)asrc; pa1 = *(const uint4*)(asrc + 8); }
  pb0 = *(const uint4*)bsrc; pb1 = *(const uint4*)(bsrc + 8);

  for (int kk = 0; kk < HID; kk += 32) {
    __syncthreads();
    *(uint4*)wAp       = pa0;
    *(uint4*)(wAp + 8) = pa1;
    *(uint4*)wBp       = pb0;
    *(uint4*)(wBp + 8) = pb1;
    __syncthreads();
    if (kk + 32 < HID) {
      if (asrc) {
        pa0 = *(const uint4*)(asrc + kk + 32);
        pa1 = *(const uint4*)(asrc + kk + 32 + 8);
      }
      pb0 = *(const uint4*)(bsrc + kk + 32);
      pb1 = *(const uint4*)(bsrc + kk + 32 + 8);
    }
    short8 a[4], bb[4];
#pragma unroll
    for (int i = 0; i < 4; i++) a[i] = *(const short8*)(rA + i * 16 * 40);
#pragma unroll
    for (int j = 0; j < 4; j++) bb[j] = *(const short8*)(rB + j * 16 * 40);
#pragma unroll
    for (int i = 0; i < 4; i++)
#pragma unroll
      for (int j = 0; j < 4; j++)
        acc[i][j] = __builtin_amdgcn_mfma_f32_16x16x32_bf16(a[i], bb[j], acc[i][j], 0, 0, 0);
  }
#pragma unroll
  for (int i = 0; i < 4; i++) {
#pragma unroll
    for (int r = 0; r < 4; r++) {
      int gr = mt * 128 + wr * 64 + i * 16 + q * 4 + r;
      if (gr < MTOT) {
        size_t rb = (size_t)gr * HID;
#pragma unroll
        for (int j = 0; j < 4; j++)
          P[rb + nt * 128 + wc * 64 + j * 16 + c] = f2bf(acc[i][j][r]);
      }
    }
  }
}

// ---------------------------------------------------------------------------
// shared staging: 64x64 bf16 slab of P (rows clamped), stride 72
// ---------------------------------------------------------------------------
__device__ __forceinline__ void stage_bf(
    us* Xs, const us* P, int b, int r0, int h, int tid) {
#pragma unroll
  for (int i = 0; i < 2; i++) {
    int idx = tid + i * 256;
    int row = idx >> 3, qq = idx & 7;
    *(uint4*)&Xs[row * 72 + qq * 8] =
        *(const uint4*)(P + ((size_t)(b * MM + min(r0 + row, MM - 1))) * HID + h * DH + qq * 8);
  }
}

// ---------------------------------------------------------------------------
// K2 (r10): sums_v4 — serialization-free body. Same (b,h,128-col-chunk)
// geometry + XCD remap as v3 (1280 = 8*160). Changes vs v3:
//  * colAcc in registers across all 9 mt; single q-reduce at end
//  * NO LDS atomics: per-strip cS2 / per-cgrp rS2 slabs, plain stores
//  * global atomics: 288 rounds -> 2 (rows); columns plain store (owned)
//  * Xs double-buffered: 1 barrier/mt (10 total vs 18)
// ---------------------------------------------------------------------------
__global__ __launch_bounds__(512) void sums_v4(
    const us* __restrict__ Px, const us* __restrict__ Py,
    const int* __restrict__ mx, const int* __restrict__ my,
    float* __restrict__ Sums) {
  const int lin = blockIdx.x;
  const int work = (lin & 7) * 160 + (lin >> 3);
  const int b = work / 80;
  const int rem = work - b * 80;
  const int h = rem / 5;
  const int nc = rem - h * 5;       // 128-col chunk index, 0..4
  const int n0 = nc * 128;
  __shared__ __align__(16) us Ys[128 * 72];      // 18.4 KB
  __shared__ __align__(16) us Xs[2][64 * 72];    // 18.4 KB (double buffer)
  __shared__ float cS2[4][128];                  //  2.0 KB (per-strip)
  __shared__ float rS2[2][576];                  //  4.6 KB (per-cgrp)
  __shared__ int myS[128];
  __shared__ int mxS[576];
  const int tid = threadIdx.x;
  const int lane = tid & 63, wave = tid >> 6;
  const int c = lane & 15, q = lane >> 4;
  const int strip = wave & 3, cgrp = wave >> 2;   // cgrp picks 64-col half
  const int row8 = tid >> 3, qq = tid & 7;        // staging map

  for (int i = tid; i < 128; i += 512) {
    int n = n0 + i;
    myS[i] = (n >= MM) ? 0 : ((n < 2) ? 1 : my[b * SEQ + n - 2]);
  }
  for (int i = tid; i < 576; i += 512)
    mxS[i] = (i >= MM) ? 0 : ((i < 2) ? 1 : mx[b * SEQ + i - 2]);
  {
    // stage Y chunk: 128 rows x 8 qq-chunks = 1024 units, 2/thread
#pragma unroll
    for (int it = 0; it < 2; it++) {
      int idx = tid + it * 512;
      int row = idx >> 3, q8 = idx & 7;
      int grow = min(n0 + row, MM - 1);
      *(uint4*)&Ys[row * 72 + q8 * 8] =
          *(const uint4*)(Py + ((size_t)(b * MM + grow)) * HID + h * DH + q8 * 8);
    }
  }
  {
    // stage X tile for mt=0 into buffer 0
    int grow = min(row8, MM - 1);
    *(uint4*)&Xs[0][row8 * 72 + qq * 8] =
        *(const uint4*)(Px + ((size_t)(b * MM + grow)) * HID + h * DH + qq * 8);
  }
  __syncthreads();

  const size_t base = ((size_t)(b * NH + h)) * MM;
  const size_t COLOFF = (size_t)B_ * NH * MM;

  // loop-invariant column masks -> registers
  int myReg[4];
#pragma unroll
  for (int ss = 0; ss < 4; ss++) myReg[ss] = myS[cgrp * 64 + ss * 16 + c];

  float colAcc[4] = {0.f, 0.f, 0.f, 0.f};

  for (int mt = 0; mt < 9; mt++) {
    const us* xb = &Xs[mt & 1][0];
    // issue next X tile load early (hides under MFMA+exp)
    uint4 nx = {0u, 0u, 0u, 0u};
    if (mt + 1 < 9) {
      int grow = min((mt + 1) * 64 + row8, MM - 1);
      nx = *(const uint4*)(Px + ((size_t)(b * MM + grow)) * HID + h * DH + qq * 8);
    }
    short8 a0 = *(const short8*)&xb[(strip * 16 + c) * 72 + q * 8];
    short8 a1 = *(const short8*)&xb[(strip * 16 + c) * 72 + q * 8 + 32];
    int rm[4];
#pragma unroll
    for (int r = 0; r < 4; r++) rm[r] = mxS[mt * 64 + strip * 16 + q * 4 + r];
    float rowp[4] = {0.f, 0.f, 0.f, 0.f};
#pragma unroll
    for (int ss = 0; ss < 4; ss++) {
      int nloc = cgrp * 64 + ss * 16 + c;
      short8 b0 = *(const short8*)&Ys[nloc * 72 + q * 8];
      short8 b1 = *(const short8*)&Ys[nloc * 72 + q * 8 + 32];
      f32x4 av = (f32x4){0.f, 0.f, 0.f, 0.f};
      av = __builtin_amdgcn_mfma_f32_16x16x32_bf16(a0, b0, av, 0, 0, 0);
      av = __builtin_amdgcn_mfma_f32_16x16x32_bf16(a1, b1, av, 0, 0, 0);
#pragma unroll
      for (int r = 0; r < 4; r++) {
        float e = (rm[r] && myReg[ss]) ? __expf(av[r]) : 0.f;
        rowp[r] += e;
        colAcc[ss] += e;
      }
    }
    // rowp reduce over the 16 c lanes; rows unique per (cgrp,strip,q,r,mt)
#pragma unroll
    for (int d = 1; d < 16; d <<= 1)
#pragma unroll
      for (int r = 0; r < 4; r++) rowp[r] += __shfl_xor(rowp[r], d, 16);
    if (c == 0) {
#pragma unroll
      for (int r = 0; r < 4; r++)
        rS2[cgrp][mt * 64 + strip * 16 + q * 4 + r] = rowp[r];
    }
    if (mt + 1 < 9)
      *(uint4*)&Xs[(mt + 1) & 1][row8 * 72 + qq * 8] = nx;
    __syncthreads();   // next X buffer ready; rS2 ordering for epilogue
  }

  // column epilogue: q-reduce once, per-strip slab, then cross-strip sum
#pragma unroll
  for (int ss = 0; ss < 4; ss++) {
    colAcc[ss] += __shfl_xor(colAcc[ss], 16);
    colAcc[ss] += __shfl_xor(colAcc[ss], 32);
  }
  if (q == 0) {
#pragma unroll
    for (int ss = 0; ss < 4; ss++)
      cS2[strip][cgrp * 64 + ss * 16 + c] = colAcc[ss];
  }
  __syncthreads();
  for (int i = tid; i < 128; i += 512) {
    int n = n0 + i;
    if (n < MM)   // block owns its column chunk -> plain store (Sums pre-zeroed)
      Sums[COLOFF + base + n] = cS2[0][i] + cS2[1][i] + cS2[2][i] + cS2[3][i];
  }
  for (int i = tid; i < 576; i += 512) {
    if (i < MM) atomicAdd(&Sums[base + i], rS2[0][i] + rS2[1][i]);
  }
}

// ---------------------------------------------------------------------------
// K2b: invert sums in place (unchanged)
// ---------------------------------------------------------------------------
__global__ __launch_bounds__(256) void inv_kernel(float* __restrict__ Sums) {
  int i = blockIdx.x * 256 + threadIdx.x;
  if (i < 2 * B_ * NH * MM) {
    float s = Sums[i];
    Sums[i] = (s > 0.f) ? (1.f / s) : -1.f;
  }
}

// ---------------------------------------------------------------------------
// K3: attn — r6-verified 64x64/256-thread body + XCD-chunked remap
// (unchanged from r8 — verified 365us run)
// ---------------------------------------------------------------------------
__global__ __launch_bounds__(256) void attn_swz(
    const us* __restrict__ Px, const us* __restrict__ Py,
    const int* __restrict__ mx, const int* __restrict__ my,
    const float* __restrict__ Inv,
    us* __restrict__ attnXT, us* __restrict__ attnY) {
  const int lin = blockIdx.x;
  const int work = (lin & 7) * 162 + (lin >> 3);
  const int b = work / 81;
  const int rem = work - b * 81;
  const int mt = rem / 9;
  const int nt = rem - mt * 9;
  __shared__ __align__(16) us Xs[64 * 72];
  __shared__ __align__(16) us Ys[64 * 72];
  const int tid = threadIdx.x;
  const int lane = tid & 63, wave = tid >> 6;
  const int c = lane & 15, q = lane >> 4;
  const size_t COLOFF = (size_t)B_ * NH * MM;

  int mreg[4], rm[4], ncol[4], cm[4];
#pragma unroll
  for (int r = 0; r < 4; r++) {
    mreg[r] = mt * 64 + wave * 16 + q * 4 + r;
    rm[r] = (mreg[r] >= MM) ? 0 : ((mreg[r] < 2) ? 1 : mx[b * SEQ + mreg[r] - 2]);
  }
#pragma unroll
  for (int s = 0; s < 4; s++) {
    ncol[s] = nt * 64 + s * 16 + c;
    cm[s] = (ncol[s] >= MM) ? 0 : ((ncol[s] < 2) ? 1 : my[b * SEQ + ncol[s] - 2]);
  }

  float aX[4][4], aY[4][4];
#pragma unroll
  for (int s = 0; s < 4; s++)
#pragma unroll
    for (int r = 0; r < 4; r++) { aX[s][r] = 0.f; aY[s][r] = 0.f; }

  for (int h = 0; h < NH; h++) {
    __syncthreads();
    stage_bf(Xs, Px, b, mt * 64, h, tid);
    stage_bf(Ys, Py, b, nt * 64, h, tid);
    __syncthreads();
    short8 a0 = *(const short8*)&Xs[(wave * 16 + c) * 72 + q * 8];
    short8 a1 = *(const short8*)&Xs[(wave * 16 + c) * 72 + q * 8 + 32];
    const size_t base = ((size_t)(b * NH + h)) * MM;
    float invR[4];
#pragma unroll
    for (int r = 0; r < 4; r++) invR[r] = Inv[base + min(mreg[r], MM - 1)];
#pragma unroll
    for (int s = 0; s < 4; s++) {
      float invC = Inv[COLOFF + base + min(ncol[s], MM - 1)];
      short8 b0 = *(const short8*)&Ys[(s * 16 + c) * 72 + q * 8];
      short8 b1 = *(const short8*)&Ys[(s * 16 + c) * 72 + q * 8 + 32];
      f32x4 av = (f32x4){0.f, 0.f, 0.f, 0.f};
      av = __builtin_amdgcn_mfma_f32_16x16x32_bf16(a0, b0, av, 0, 0, 0);
      av = __builtin_amdgcn_mfma_f32_16x16x32_bf16(a1, b1, av, 0, 0, 0);
#pragma unroll
      for (int r = 0; r < 4; r++) {
        float e = (rm[r] && cm[s]) ? __expf(av[r]) : 0.f;
        aY[s][r] += (invR[r] < 0.f) ? UNI : e * invR[r];
        aX[s][r] += (invC < 0.f) ? UNI : e * invC;
      }
    }
  }
#pragma unroll
  for (int s = 0; s < 4; s++) {
    if (ncol[s] < MM) {
      us* xrow = attnXT + ((size_t)(b * MM + ncol[s])) * KP;
      if (mreg[3] < MM) {   // fast packed 4xf16 store (mreg[0] % 4 == 0)
        uint2 w;
        w.x = (unsigned)f2h(aX[s][0] * 0.0625f) | ((unsigned)f2h(aX[s][1] * 0.0625f) << 16);
        w.y = (unsigned)f2h(aX[s][2] * 0.0625f) | ((unsigned)f2h(aX[s][3] * 0.0625f) << 16);
        *(uint2*)&xrow[mreg[0]] = w;
      } else {
#pragma unroll
        for (int r = 0; r < 4; r++)
          if (mreg[r] < MM) xrow[mreg[r]] = f2h(aX[s][r] * 0.0625f);
      }
#pragma unroll
      for (int r = 0; r < 4; r++)
        if (mreg[r] < MM)
          attnY[((size_t)(b * MM + mreg[r])) * KP + ncol[s]] = f2h(aY[s][r] * 0.0625f);
    }
  }
}

// ---------------------------------------------------------------------------
// K3b (fused): XT[b][o][k] = f16(Mem(k,o)) for both paths (unchanged)
// ---------------------------------------------------------------------------
__global__ __launch_bounds__(256) void transpose_fused(
    const float* __restrict__ x, const float* __restrict__ y,
    const float* __restrict__ xm, const float* __restrict__ ym,
    us* __restrict__ XTx, us* __restrict__ XTy) {
  const int kt = blockIdx.x, ot = blockIdx.y;
  const int b = blockIdx.z & 15, path = blockIdx.z >> 4;
  const float* tin  = path ? y  : x;
  const float* mvec = path ? ym : xm;
  us* XT            = path ? XTy : XTx;
  __shared__ __align__(16) us T[64 * 40];
  const int tid = threadIdx.x;
  {
    const int row = tid >> 3;          // k-local 0..31
    const int col8 = (tid & 7) * 8;    // o-local chunk
    const int kg = kt * 32 + row;
    const float* src = (kg < 2) ? (mvec + (size_t)kg * HID + ot * 64 + col8)
                     : (kg < MM) ? (tin + ((size_t)(b * SEQ + kg - 2)) * HID + ot * 64 + col8)
                                 : nullptr;
    f32x4 v0 = (f32x4){0.f, 0.f, 0.f, 0.f};
    f32x4 v1 = (f32x4){0.f, 0.f, 0.f, 0.f};
    if (src) { v0 = *(const f32x4*)src; v1 = *(const f32x4*)(src + 4); }
#pragma unroll
    for (int j = 0; j < 4; j++) T[(col8 + j) * 40 + row] = f2h(v0[j]);
#pragma unroll
    for (int j = 0; j < 4; j++) T[(col8 + 4 + j) * 40 + row] = f2h(v1[j]);
  }
  __syncthreads();
  const int orow = tid >> 2, kc = (tid & 3) * 8;
  uint4 w = *(const uint4*)&T[orow * 40 + kc];
  *(uint4*)&XT[((size_t)(b * HID + ot * 64 + orow)) * KP + kt * 32 + kc] = w;
}

// ---------------------------------------------------------------------------
// K4 (fused): MFMA output GEMM for both paths (unchanged)
// ---------------------------------------------------------------------------
__global__ __launch_bounds__(256) void outg_fused(
    const us* __restrict__ A0, const us* __restrict__ A1,
    const us* __restrict__ XTx, const us* __restrict__ XTy,
    float* __restrict__ outp) {
  const int ot = blockIdx.x, rt = blockIdx.y;
  const int b = blockIdx.z & 15, path = blockIdx.z >> 4;
  const us* A  = path ? A1 : A0;
  const us* XT = path ? XTy : XTx;
  float* op = outp + (path ? (size_t)B_ * SEQ * HID : 0);
  const int r0 = rt * 128, o0 = ot * 128;
  __shared__ __align__(16) us As[128 * 40];
  __shared__ __align__(16) us Bs[128 * 40];
  const int tid = threadIdx.x;
  const int lane = tid & 63, wave = tid >> 6;
  const int c = lane & 15, q = lane >> 4;
  const int wr = wave >> 1, wc = wave & 1;

  const int srow = tid >> 2, sch = (tid & 3) * 8;
  const us* gA0 = A + ((size_t)(b * MM + 2 + r0 + srow)) * KP + sch;
  const us* gA1 = gA0 + (size_t)64 * KP;
  const us* gB0 = XT + ((size_t)(b * HID + o0 + srow)) * KP + sch;
  const us* gB1 = gB0 + (size_t)64 * KP;
  us* wA0 = &As[srow * 40 + sch];
  us* wA1 = wA0 + 64 * 40;
  us* wB0 = &Bs[srow * 40 + sch];
  us* wB1 = wB0 + 64 * 40;

  f32x4 acc[4][4];
#pragma unroll
  for (int i = 0; i < 4; i++)
#pragma unroll
    for (int j = 0; j < 4; j++) acc[i][j] = (f32x4){0.f, 0.f, 0.f, 0.f};

  const us* rA = &As[(wr * 64 + c) * 40 + q * 8];
  const us* rB = &Bs[(wc * 64 + c) * 40 + q * 8];

  uint4 pA0 = *(const uint4*)gA0;
  uint4 pA1 = *(const uint4*)gA1;
  uint4 pB0 = *(const uint4*)gB0;
  uint4 pB1 = *(const uint4*)gB1;

  for (int kk = 0; kk < KP; kk += 32) {
    __syncthreads();
    *(uint4*)wA0 = pA0;
    *(uint4*)wA1 = pA1;
    *(uint4*)wB0 = pB0;
    *(uint4*)wB1 = pB1;
    __syncthreads();
    if (kk + 32 < KP) {
      pA0 = *(const uint4*)(gA0 + kk + 32);
      pA1 = *(const uint4*)(gA1 + kk + 32);
      pB0 = *(const uint4*)(gB0 + kk + 32);
      pB1 = *(const uint4*)(gB1 + kk + 32);
    }
    half8 a[4], bb[4];
#pragma unroll
    for (int i = 0; i < 4; i++) a[i] = *(const half8*)(rA + i * 16 * 40);
#pragma unroll
    for (int j = 0; j < 4; j++) bb[j] = *(const half8*)(rB + j * 16 * 40);
#pragma unroll
    for (int i = 0; i < 4; i++)
#pragma unroll
      for (int j = 0; j < 4; j++)
        acc[i][j] = __builtin_amdgcn_mfma_f32_16x16x32_f16(a[i], bb[j], acc[i][j], 0, 0, 0);
  }
#pragma unroll
  for (int i = 0; i < 4; i++) {
#pragma unroll
    for (int rr = 0; rr < 4; rr++) {
      int r = r0 + wr * 64 + i * 16 + q * 4 + rr;
      size_t rowbase = ((size_t)(b * SEQ + r)) * HID;
#pragma unroll
      for (int j = 0; j < 4; j++)
        op[rowbase + o0 + wc * 64 + j * 16 + c] = acc[i][j][rr];
    }
  }
}

// ---------------------------------------------------------------------------
// Fallback path kernels (old bf16 attn + f32 outg)
// ---------------------------------------------------------------------------
__global__ __launch_bounds__(256) void attn_mfma_old(
    const us* __restrict__ Px, const us* __restrict__ Py,
    const int* __restrict__ mx, const int* __restrict__ my,
    const float* __restrict__ Inv,
    us* __restrict__ attnX, us* __restrict__ attnY,
    const int doX, const int doY) {
  const int nt = blockIdx.x, mt = blockIdx.y, b = blockIdx.z;
  __shared__ __align__(16) us Xs[64 * 72];
  __shared__ __align__(16) us Ys[64 * 72];
  const int tid = threadIdx.x;
  const int lane = tid & 63, wave = tid >> 6;
  const int c = lane & 15, q = lane >> 4;
  const size_t COLOFF = (size_t)B_ * NH * MM;

  int mreg[4], rm[4], ncol[4], cm[4];
#pragma unroll
  for (int r = 0; r < 4; r++) {
    mreg[r] = mt * 64 + wave * 16 + q * 4 + r;
    rm[r] = (mreg[r] >= MM) ? 0 : ((mreg[r] < 2) ? 1 : mx[b * SEQ + mreg[r] - 2]);
  }
#pragma unroll
  for (int s = 0; s < 4; s++) {
    ncol[s] = nt * 64 + s * 16 + c;
    cm[s] = (ncol[s] >= MM) ? 0 : ((ncol[s] < 2) ? 1 : my[b * SEQ + ncol[s] - 2]);
  }

  float aX[4][4], aY[4][4];
#pragma unroll
  for (int s = 0; s < 4; s++)
#pragma unroll
    for (int r = 0; r < 4; r++) { aX[s][r] = 0.f; aY[s][r] = 0.f; }

  for (int h = 0; h < NH; h++) {
    __syncthreads();
    stage_bf(Xs, Px, b, mt * 64, h, tid);
    stage_bf(Ys, Py, b, nt * 64, h, tid);
    __syncthreads();
    short8 a0 = *(const short8*)&Xs[(wave * 16 + c) * 72 + q * 8];
    short8 a1 = *(const short8*)&Xs[(wave * 16 + c) * 72 + q * 8 + 32];
    const size_t base = ((size_t)(b * NH + h)) * MM;
    float invR[4];
#pragma unroll
    for (int r = 0; r < 4; r++) invR[r] = Inv[base + min(mreg[r], MM - 1)];
#pragma unroll
    for (int s = 0; s < 4; s++) {
      float invC = Inv[COLOFF + base + min(ncol[s], MM - 1)];
      short8 b0 = *(const short8*)&Ys[(s * 16 + c) * 72 + q * 8];
      short8 b1 = *(const short8*)&Ys[(s * 16 + c) * 72 + q * 8 + 32];
      f32x4 av = (f32x4){0.f, 0.f, 0.f, 0.f};
      av = __builtin_amdgcn_mfma_f32_16x16x32_bf16(a0, b0, av, 0, 0, 0);
      av = __builtin_amdgcn_mfma_f32_16x16x32_bf16(a1, b1, av, 0, 0, 0);
#pragma unroll
      for (int r = 0; r < 4; r++) {
        float e = (rm[r] && cm[s]) ? __expf(av[r]) : 0.f;
        aY[s][r] += (invR[r] < 0.f) ? UNI : e * invR[r];
        aX[s][r] += (invC < 0.f) ? UNI : e * invC;
      }
    }
  }
#pragma unroll
  for (int s = 0; s < 4; s++) {
#pragma unroll
    for (int r = 0; r < 4; r++) {
      if (mreg[r] < MM && ncol[s] < MM) {
        size_t idx = ((size_t)(b * MM + mreg[r])) * MM + ncol[s];
        if (doX) attnX[idx] = f2bf(aX[s][r] * 0.0625f);
        if (doY) attnY[idx] = f2bf(aY[s][r] * 0.0625f);
      }
    }
  }
}

__global__ __launch_bounds__(256) void outg_kernel(
    const us* __restrict__ attn, const float* __restrict__ tin,
    const float* __restrict__ mvec, float* __restrict__ outp, const int trans) {
  const int otile = blockIdx.x, rtile = blockIdx.y, b = blockIdx.z;
  __shared__ __align__(16) float Ss[32 * 132];
  __shared__ __align__(16) float Ms[32 * 132];
  const int tid = threadIdx.x;
  const int r0 = rtile * 128, o0 = otile * 128;

  float acc[8][8];
#pragma unroll
  for (int i = 0; i < 8; i++)
#pragma unroll
    for (int j = 0; j < 8; j++) acc[i][j] = 0.f;

  for (int kk = 0; kk < 544; kk += 32) {
    __syncthreads();
    if (trans) {
      int rq = (tid & 31) * 4;
      int kr = tid >> 5;
#pragma unroll
      for (int kb = 0; kb < 32; kb += 8) {
        int k = kr + kb;
        int kg = kk + k;
        if (kg < MM) {
          const us* src = attn + ((size_t)(b * MM + kg)) * MM + 2 + r0 + rq;
          Ss[k * 132 + rq + 0] = bf2f(src[0]);
          Ss[k * 132 + rq + 1] = bf2f(src[1]);
          Ss[k * 132 + rq + 2] = bf2f(src[2]);
          Ss[k * 132 + rq + 3] = bf2f(src[3]);
        } else {
          Ss[k * 132 + rq + 0] = 0.f;
          Ss[k * 132 + rq + 1] = 0.f;
          Ss[k * 132 + rq + 2] = 0.f;
          Ss[k * 132 + rq + 3] = 0.f;
        }
      }
    } else {
      int r = tid >> 1;
      int kh = (tid & 1) * 16;
      const us* src = attn + ((size_t)(b * MM + 2 + r0 + r)) * MM;
#pragma unroll
      for (int j = 0; j < 16; j++) {
        int k = kh + j;
        int kg = kk + k;
        Ss[k * 132 + r] = (kg < MM) ? bf2f(src[kg]) : 0.f;
      }
    }
    {
      int k = tid >> 3;
      int oq = (tid & 7) * 16;
      int kg = kk + k;
      const float* mr = (kg < 2) ? (mvec + (size_t)kg * HID)
                      : (kg < MM) ? (tin + ((size_t)(b * SEQ + kg - 2)) * HID)
                                  : nullptr;
#pragma unroll
      for (int qq = 0; qq < 4; qq++) {
        f32x4 v = (f32x4){0.f, 0.f, 0.f, 0.f};
        if (mr) v = *(const f32x4*)(mr + o0 + oq + qq * 4);
        *(f32x4*)&Ms[k * 132 + oq + qq * 4] = v;
      }
    }
    __syncthreads();
    const int ty = tid >> 4, tx = tid & 15;
    for (int k = 0; k < 32; k++) {
      f32x4 s0 = *(const f32x4*)&Ss[k * 132 + ty * 4];
      f32x4 s1 = *(const f32x4*)&Ss[k * 132 + 64 + ty * 4];
      f32x4 m0 = *(const f32x4*)&Ms[k * 132 + tx * 4];
      f32x4 m1 = *(const f32x4*)&Ms[k * 132 + 64 + tx * 4];
#pragma unroll
      for (int i = 0; i < 4; i++) {
#pragma unroll
        for (int j = 0; j < 4; j++) {
          acc[i][j]         += s0[i] * m0[j];
          acc[i][j + 4]     += s0[i] * m1[j];
          acc[i + 4][j]     += s1[i] * m0[j];
          acc[i + 4][j + 4] += s1[i] * m1[j];
        }
      }
    }
  }
  const int ty = tid >> 4, tx = tid & 15;
#pragma unroll
  for (int ri = 0; ri < 2; ri++) {
#pragma unroll
    for (int i = 0; i < 4; i++) {
      int r = r0 + ri * 64 + ty * 4 + i;
      size_t rowbase = ((size_t)(b * SEQ + r)) * HID;
#pragma unroll
      for (int oi = 0; oi < 2; oi++) {
        int o = o0 + oi * 64 + tx * 4;
        f32x4 v;
#pragma unroll
        for (int j = 0; j < 4; j++) v[j] = acc[ri * 4 + i][oi * 4 + j];
        *(f32x4*)&outp[rowbase + o] = v;
      }
    }
  }
}

// ---------------------------------------------------------------------------
extern "C" void kernel_launch(void* const* d_in, const int* in_sizes, int n_in,
                              void* d_out, int out_size, void* d_ws, size_t ws_size,
                              hipStream_t stream) {
  const float* x  = (const float*)d_in[0];
  const float* y  = (const float*)d_in[1];
  const int* mask_x = (const int*)d_in[2];
  const int* mask_y = (const int*)d_in[3];
  const float* Wx = (const float*)d_in[4];
  const float* Wy = (const float*)d_in[5];
  const float* xm = (const float*)d_in[6];
  const float* ym = (const float*)d_in[7];
  float* out = (float*)d_out;

  const size_t szSums = (size_t)2 * B_ * NH * MM * 4;   //  1,052,672
  const size_t szP    = (size_t)B_ * MM * HID * 2;      // 16,842,752 (bf16)
  const size_t szAtt  = (size_t)B_ * MM * MM * 2;       //  8,454,272 (bf16, old)
  const size_t szAttP = (size_t)B_ * MM * KP * 2;       //  8,947,712 (f16, padded)
  const size_t szXT   = (size_t)B_ * HID * KP * 2;      // 17,825,792 (f16)
  const size_t R_off  = szSums + 2 * szAttP;            // P / XT region start
  const size_t needNew = R_off + 2 * szXT;              // 54,599,680

  char* ws = (char*)d_ws;

  // prepack scratch lives in d_out (67 MB; dead until outg rewrites all of it)
  us* Abf = (us*)d_out;                                  // 33.7 MB
  us* Wbf = (us*)d_out + (size_t)2 * MTOT * HID;         //  4.2 MB

  if (ws_size >= needNew) {
    // ---- MFMA output path ----
    float* Sums = (float*)ws;
    us* A0  = (us*)(ws + szSums);            // attnX transposed, [MM][KP] f16
    us* A1  = (us*)(ws + szSums + szAttP);   // attnY,           [MM][KP] f16
    us* Px  = (us*)(ws + R_off);
    us* Py  = (us*)(ws + R_off + szP);
    us* XTx = (us*)(ws + R_off);             // overlaps Px/Py — P dead by then
    us* XTy = (us*)(ws + R_off + szXT);

    prepack<<<dim3((MTOT + HID) / 4, 2), 256, 0, stream>>>(x, y, xm, ym, Wx, Wy, Abf, Wbf);
    proj_fused2<<<dim3(8, 65, 2), 256, 0, stream>>>(Abf, Wbf, Px, Py);
    hipMemsetAsync(Sums, 0, szSums, stream);
    hipMemsetAsync(A0, 0, 2 * szAttP, stream);   // zero pad cols for K-tail
    sums_v4<<<dim3(1280), 512, 0, stream>>>(Px, Py, mask_x, mask_y, Sums);
    inv_kernel<<<dim3((2 * B_ * NH * MM + 255) / 256), 256, 0, stream>>>(Sums);
    attn_swz<<<dim3(1296), 256, 0, stream>>>(Px, Py, mask_x, mask_y, Sums, A0, A1);
    transpose_fused<<<dim3(17, 16, 32), 256, 0, stream>>>(x, y, xm, ym, XTx, XTy);
    outg_fused<<<dim3(8, 4, 32), 256, 0, stream>>>(A0, A1, XTx, XTy, out);
    return;
  }

  // ---- fallback: previous verified path ----
  const int dual = (ws_size >= szSums + 2 * szP + 2 * szAtt) ? 1 : 0;
  float* Sums = (float*)(ws);
  us* Px = (us*)(ws + szSums);
  us* Py = (us*)(ws + szSums + szP);
  us* A0 = (us*)(ws + szSums + 2 * szP);
  us* A1 = dual ? (us*)(ws + szSums + 2 * szP + szAtt) : A0;

  prepack<<<dim3((MTOT + HID) / 4, 2), 256, 0, stream>>>(x, y, xm, ym, Wx, Wy, Abf, Wbf);
  proj_fused2<<<dim3(8, 65, 2), 256, 0, stream>>>(Abf, Wbf, Px, Py);
  hipMemsetAsync(Sums, 0, szSums, stream);
  sums_v4<<<dim3(1280), 512, 0, stream>>>(Px, Py, mask_x, mask_y, Sums);
  inv_kernel<<<dim3((2 * B_ * NH * MM + 255) / 256), 256, 0, stream>>>(Sums);

  if (dual) {
    attn_mfma_old<<<dim3(9, 9, 16), 256, 0, stream>>>(Px, Py, mask_x, mask_y, Sums, A0, A1, 1, 1);
    outg_kernel<<<dim3(8, 4, 16), 256, 0, stream>>>(A0, x, xm, out, 1);
    outg_kernel<<<dim3(8, 4, 16), 256, 0, stream>>>(A1, y, ym, out + (size_t)B_ * SEQ * HID, 0);
  } else {
    attn_mfma_old<<<dim3(9, 9, 16), 256, 0, stream>>>(Px, Py, mask_x, mask_y, Sums, A0, A0, 1, 0);
    outg_kernel<<<dim3(8, 4, 16), 256, 0, stream>>>(A0, x, xm, out, 1);
    attn_mfma_old<<<dim3(9, 9, 16), 256, 0, stream>>>(Px, Py, mask_x, mask_y, Sums, A0, A0, 0, 1);
    outg_kernel<<<dim3(8, 4, 16), 256, 0, stream>>>(A0, y, ym, out + (size_t)B_ * SEQ * HID, 0);
  }
}